// Round 4
// baseline (559.569 us; speedup 1.0000x reference)
//
#include <hip/hip_runtime.h>
#include <hip/hip_cooperative_groups.h>
#include <math.h>

namespace cg = cooperative_groups;

#define NHID 1024
#define NOUT 50257
#define MAXLEN 24

// ws layout (float offsets)
#define WS_APP   0        // attn_applied [1024]
#define WS_X     1024     // relu(comb out) [1024]
#define WS_GH    2048     // W_hh @ h + b_hh [3072]
#define WS_H     5120     // h_new [1024]
#define WS_LOGIT 8192     // logits [50257]
#define WS_PAIRS 61440    // 256 (m,s) pairs

#define NBLK 256
#define NGROUP 786        // ceil(50257/64) row-groups of 64

__device__ __forceinline__ float wave_reduce_sum(float v) {
    #pragma unroll
    for (int off = 32; off > 0; off >>= 1) v += __shfl_down(v, off, 64);
    return v;
}

__device__ __forceinline__ void lse_merge(float& m, float& s, float m2, float s2) {
    float M = fmaxf(m, m2);
    s = s * expf(m - M) + s2 * expf(m2 - M);
    m = M;
}

__global__ __launch_bounds__(1024) void
k_fused(const int* __restrict__ inp, const float* __restrict__ hid,
        const float* __restrict__ enc, const float* __restrict__ embW,
        const float* __restrict__ attnW, const float* __restrict__ attnb,
        const float* __restrict__ combW, const float* __restrict__ combb,
        const float* __restrict__ Wih, const float* __restrict__ Whh,
        const float* __restrict__ bih, const float* __restrict__ bhh,
        const float* __restrict__ outW, const float* __restrict__ outb,
        float* __restrict__ ws, float* __restrict__ out) {
    cg::grid_group grid = cg::this_grid();
    const int tid = threadIdx.x;
    const int lane = tid & 63, wave = tid >> 6;
    const int bid = blockIdx.x;
    const int gwave = bid * 16 + wave;

    __shared__ float s_sc[MAXLEN], s_w[MAXLEN];
    __shared__ float sm[16], ss[16];
    __shared__ float sC;

    const float4* hid4 = (const float4*)hid;
    const float4* emb4 = (const float4*)(embW + (size_t)inp[0] * NHID);

    // ---- Phase A: block 0 = attention; blocks 1..192 = gh = W_hh@h + b_hh ----
    if (bid == 0) {
        for (int i = wave; i < MAXLEN; i += 16) {
            const float4* w4 = (const float4*)(attnW + (size_t)i * 2 * NHID);
            float acc = 0.f;
            #pragma unroll
            for (int it = 0; it < 8; ++it) {
                int idx = it * 64 + lane;                 // [0,512) float4
                float4 w = w4[idx];
                float4 a = (idx < 256) ? emb4[idx] : hid4[idx - 256];
                acc += w.x * a.x + w.y * a.y + w.z * a.z + w.w * a.w;
            }
            acc = wave_reduce_sum(acc);
            if (lane == 0) s_sc[i] = acc + attnb[i];
        }
        __syncthreads();
        if (tid == 0) {
            float m = -1e30f;
            for (int i = 0; i < MAXLEN; ++i) m = fmaxf(m, s_sc[i]);
            float s = 0.f;
            for (int i = 0; i < MAXLEN; ++i) { float e = expf(s_sc[i] - m); s_w[i] = e; s += e; }
            float inv = 1.f / s;
            for (int i = 0; i < MAXLEN; ++i) { s_w[i] *= inv; out[NOUT + NHID + i] = s_w[i]; }
        }
        __syncthreads();
        float acc = 0.f;
        #pragma unroll 4
        for (int i = 0; i < MAXLEN; ++i) acc += s_w[i] * enc[i * NHID + tid];
        ws[WS_APP + tid] = acc;
    } else if (bid <= 192) {
        const int row = (bid - 1) * 16 + wave;            // 0..3071
        const float4* w4 = (const float4*)(Whh + (size_t)row * NHID);
        float acc = 0.f;
        #pragma unroll
        for (int it = 0; it < 4; ++it) {
            int idx = it * 64 + lane;
            float4 w = w4[idx], h = hid4[idx];
            acc += w.x * h.x + w.y * h.y + w.z * h.z + w.w * h.w;
        }
        acc = wave_reduce_sum(acc);
        if (lane == 0) ws[WS_GH + row] = acc + bhh[row];
    }
    grid.sync();

    // ---- Phase B: comb rows; one wave per row j in [0,1024) ----
    if (gwave < NHID) {
        const int j = gwave;
        const float4* app4 = (const float4*)(ws + WS_APP);
        const float4* w4 = (const float4*)(combW + (size_t)j * 2 * NHID);
        float acc = 0.f;
        #pragma unroll
        for (int it = 0; it < 8; ++it) {
            int idx = it * 64 + lane;
            float4 w = w4[idx];
            float4 a = (idx < 256) ? emb4[idx] : app4[idx - 256];
            acc += w.x * a.x + w.y * a.y + w.z * a.z + w.w * a.w;
        }
        acc = wave_reduce_sum(acc);
        if (lane == 0) ws[WS_X + j] = fmaxf(acc + combb[j], 0.f);
    }
    grid.sync();

    // ---- Phase C: GRU; one wave per hidden index j ----
    if (gwave < NHID) {
        const int j = gwave;
        const float4* x4 = (const float4*)(ws + WS_X);
        float4 xv[4];
        #pragma unroll
        for (int it = 0; it < 4; ++it) xv[it] = x4[it * 64 + lane];
        float gi[3];
        #pragma unroll
        for (int r = 0; r < 3; ++r) {
            const float4* w4 = (const float4*)(Wih + (size_t)(r * NHID + j) * NHID);
            float acc = 0.f;
            #pragma unroll
            for (int it = 0; it < 4; ++it) {
                float4 w = w4[it * 64 + lane];
                acc += w.x * xv[it].x + w.y * xv[it].y + w.z * xv[it].z + w.w * xv[it].w;
            }
            gi[r] = wave_reduce_sum(acc);
        }
        if (lane == 0) {
            float ir = gi[0] + bih[j],            hr = ws[WS_GH + j];
            float iz = gi[1] + bih[NHID + j],     hz = ws[WS_GH + NHID + j];
            float in_ = gi[2] + bih[2 * NHID + j], hn = ws[WS_GH + 2 * NHID + j];
            float r_ = 1.f / (1.f + expf(-(ir + hr)));
            float z_ = 1.f / (1.f + expf(-(iz + hz)));
            float n_ = tanhf(in_ + r_ * hn);
            float hnew = (1.f - z_) * n_ + z_ * hid[j];
            ws[WS_H + j] = hnew;
            out[NOUT + j] = hnew;
        }
    }
    grid.sync();

    // ---- Phase D: logits + per-block online-LSE pair ----
    {
        const float4* h4 = (const float4*)(ws + WS_H);
        float4 hv[4];
        #pragma unroll
        for (int it = 0; it < 4; ++it) hv[it] = h4[it * 64 + lane];
        float m = -1e30f, s = 0.f;
        for (int g = bid; g < NGROUP; g += NBLK) {
            const int rowBase = g * 64 + wave * 4;
            #pragma unroll
            for (int rr = 0; rr < 4; ++rr) {
                const int row = rowBase + rr;
                if (row < NOUT) {
                    const float4* w4 = (const float4*)(outW + (size_t)row * NHID);
                    float acc = 0.f;
                    #pragma unroll
                    for (int it = 0; it < 4; ++it) {
                        float4 w = w4[it * 64 + lane];
                        acc += w.x * hv[it].x + w.y * hv[it].y + w.z * hv[it].z + w.w * hv[it].w;
                    }
                    acc = wave_reduce_sum(acc);
                    if (lane == 0) {
                        float v = acc + outb[row];
                        ws[WS_LOGIT + row] = v;
                        lse_merge(m, s, v, 1.f);
                    }
                }
            }
        }
        if (lane == 0) { sm[wave] = m; ss[wave] = s; }
        __syncthreads();
        if (tid == 0) {
            float M = sm[0], S = ss[0];
            #pragma unroll
            for (int w = 1; w < 16; ++w) lse_merge(M, S, sm[w], ss[w]);
            ws[WS_PAIRS + 2 * bid] = M;
            ws[WS_PAIRS + 2 * bid + 1] = S;
        }
    }
    grid.sync();

    // ---- Phase E: merge 256 pairs -> C; normalize ----
    if (wave == 0) {
        float m = -1e30f, s = 0.f;
        #pragma unroll
        for (int k = 0; k < 4; ++k) {
            int idx = k * 64 + lane;
            lse_merge(m, s, ws[WS_PAIRS + 2 * idx], ws[WS_PAIRS + 2 * idx + 1]);
        }
        #pragma unroll
        for (int off = 32; off > 0; off >>= 1) {
            float m2 = __shfl_down(m, off, 64);
            float s2 = __shfl_down(s, off, 64);
            lse_merge(m, s, m2, s2);
        }
        if (lane == 0) sC = m + logf(s);
    }
    __syncthreads();
    {
        const float C = sC;
        const int i = bid * 1024 + tid;                   // blocks 0..49 cover NOUT
        if (i < NOUT) out[i] = ws[WS_LOGIT + i] - C;
    }
}

extern "C" void kernel_launch(void* const* d_in, const int* in_sizes, int n_in,
                              void* d_out, int out_size, void* d_ws, size_t ws_size,
                              hipStream_t stream) {
    const int*   inp   = (const int*)d_in[0];
    const float* hid   = (const float*)d_in[1];
    // d_in[2] (encoder_output) unused by the reference.
    const float* enc   = (const float*)d_in[3];
    const float* embW  = (const float*)d_in[4];
    const float* attnW = (const float*)d_in[5];
    const float* attnb = (const float*)d_in[6];
    const float* combW = (const float*)d_in[7];
    const float* combb = (const float*)d_in[8];
    const float* Wih   = (const float*)d_in[9];
    const float* Whh   = (const float*)d_in[10];
    const float* bih   = (const float*)d_in[11];
    const float* bhh   = (const float*)d_in[12];
    const float* outW  = (const float*)d_in[13];
    const float* outb  = (const float*)d_in[14];
    float* out = (float*)d_out;
    float* ws  = (float*)d_ws;

    void* args[] = { (void*)&inp, (void*)&hid, (void*)&enc, (void*)&embW,
                     (void*)&attnW, (void*)&attnb, (void*)&combW, (void*)&combb,
                     (void*)&Wih, (void*)&Whh, (void*)&bih, (void*)&bhh,
                     (void*)&outW, (void*)&outb, (void*)&ws, (void*)&out };
    hipLaunchCooperativeKernel((void*)k_fused, dim3(NBLK), dim3(1024), args, 0, stream);
}